// Round 3
// baseline (309.790 us; speedup 1.0000x reference)
//
#include <hip/hip_runtime.h>

typedef unsigned short ushort_t;
typedef __attribute__((ext_vector_type(8))) __bf16 bf16x8;
typedef __attribute__((ext_vector_type(4))) float f32x4;
typedef __attribute__((ext_vector_type(4))) ushort_t ushort4_t;

__device__ inline ushort_t f2bf(float f){           // compiler emits v_cvt_pk_bf16_f32
  __bf16 h = (__bf16)f;
  union { __bf16 h; ushort_t u; } v; v.h = h;
  return v.u;
}

__device__ inline f32x4 mfma16(bf16x8 a, bf16x8 b, f32x4 c){
  return __builtin_amdgcn_mfma_f32_16x16x32_bf16(a, b, c, 0, 0, 0);
}

// ---------------- Kernel A1: spectral norm sigma (one block per weight) ----
__global__ void sigma_kernel(const float* __restrict__ Wf, const float* __restrict__ uf,
                             const float* __restrict__ Wg, const float* __restrict__ ug,
                             const float* __restrict__ Wh, const float* __restrict__ uh,
                             const float* __restrict__ Wc, const float* __restrict__ uc,
                             float* __restrict__ inv_sigma){
  int w = blockIdx.x, t = threadIdx.x;
  const float *W, *u; int Cout;
  if      (w == 0){ W = Wf; u = uf; Cout = 32; }
  else if (w == 1){ W = Wg; u = ug; Cout = 32; }
  else if (w == 2){ W = Wh; u = uh; Cout = 256; }
  else            { W = Wc; u = uc; Cout = 256; }
  __shared__ float su[256], sv[256], red[256];
  su[t] = u[t];
  __syncthreads();
  float v = 0.f;
  if (t < Cout){
    for (int i = 0; i < 256; ++i) v += W[i*Cout + t] * su[i];
  }
  red[t] = (t < Cout) ? v*v : 0.f;
  __syncthreads();
  for (int s = 128; s > 0; s >>= 1){ if (t < s) red[t] += red[t+s]; __syncthreads(); }
  float nv = sqrtf(red[0]) + 1e-12f;
  __syncthreads();
  if (t < Cout) sv[t] = v / nv;
  __syncthreads();
  float wv = 0.f;
  for (int d = 0; d < Cout; ++d) wv += W[t*Cout + d] * sv[d];
  __syncthreads();
  red[t] = wv * wv;
  __syncthreads();
  for (int s = 128; s > 0; s >>= 1){ if (t < s) red[t] += red[t+s]; __syncthreads(); }
  if (t == 0){
    float ss2 = red[0];
    float sig = ss2 / (sqrtf(ss2) + 1e-12f);   // sigma = u_new . (W v)
    inv_sigma[w] = 1.0f / sig;
  }
}

// ---------------- Kernel A2: transpose + 1/sigma fold + bf16 cast ----------
__global__ void prep_weights(const float* __restrict__ Wf, const float* __restrict__ Wg,
                             const float* __restrict__ Wh, const float* __restrict__ Wc,
                             const float* __restrict__ inv_sigma,
                             ushort_t* __restrict__ WallT, ushort_t* __restrict__ WcT){
  int idx = blockIdx.x * 256 + threadIdx.x;   // 0 .. 147455
  if (idx < 81920){                            // WallT[c][k], c in [0,320)
    int c = idx >> 8, k = idx & 255;
    float val, is;
    if (c < 32)      { val = Wf[k*32  + c      ]; is = inv_sigma[0]; }
    else if (c < 64) { val = Wg[k*32  + (c-32) ]; is = inv_sigma[1]; }
    else             { val = Wh[k*256 + (c-64) ]; is = inv_sigma[2]; }
    WallT[idx] = f2bf(val * is);
  } else {
    int j = idx - 81920; int c = j >> 8, k = j & 255;
    WcT[j] = f2bf(Wc[k*256 + c] * inv_sigma[3]);
  }
}

// ---------------- Kernel B: f,g,h = x @ [Wf|Wg|Wh]_sn + bias ---------------
// g (queries) is pre-scaled by log2(e) so attention softmax can use exp2.
__global__ __launch_bounds__(256) void fgh_kernel(
    const float* __restrict__ x, const ushort_t* __restrict__ WallT,
    const float* __restrict__ bf, const float* __restrict__ bg, const float* __restrict__ bh,
    ushort_t* __restrict__ fO, ushort_t* __restrict__ gO, ushort_t* __restrict__ hT){
  int t = threadIdx.x;
  int wv = t >> 6, l = t & 63, lrow = l & 15, lgrp = l >> 4;
  long r0 = (long)blockIdx.x * 64 + wv * 16;
  const float* xrow = x + (r0 + lrow) * 256;
  f32x4 acc[20];
#pragma unroll
  for (int i = 0; i < 20; ++i) acc[i] = f32x4{0.f,0.f,0.f,0.f};
#pragma unroll
  for (int ks = 0; ks < 8; ++ks){
    int kk = ks*32 + lgrp*8;
    f32x4 xa = *(const f32x4*)(xrow + kk);
    f32x4 xb = *(const f32x4*)(xrow + kk + 4);
    union { __bf16 h[8]; bf16x8 v; } A;
#pragma unroll
    for (int j = 0; j < 4; ++j){ A.h[j] = (__bf16)xa[j]; A.h[4+j] = (__bf16)xb[j]; }
#pragma unroll
    for (int ct = 0; ct < 20; ++ct){
      bf16x8 bb = *(const bf16x8*)(WallT + (ct*16 + lrow)*256 + kk);
      acc[ct] = mfma16(A.v, bb, acc[ct]);
    }
  }
#pragma unroll
  for (int ct = 0; ct < 20; ++ct){
    int col = ct*16 + lrow;
    long rowb = r0 + lgrp*4;
    if (col < 32){
      float bv = bf[col];
#pragma unroll
      for (int rg = 0; rg < 4; ++rg) fO[(rowb+rg)*32 + col] = f2bf(acc[ct][rg] + bv);
    } else if (col < 64){
      float bv = bg[col-32];
#pragma unroll
      for (int rg = 0; rg < 4; ++rg)
        gO[(rowb+rg)*32 + (col-32)] = f2bf((acc[ct][rg] + bv) * 1.44269504f);
    } else {
      int hc = col - 64;
      float bv = bh[hc];
      long bb = rowb >> 12, n = rowb & 4095;
      ushort4_t pk;
#pragma unroll
      for (int rg = 0; rg < 4; ++rg) pk[rg] = f2bf(acc[ct][rg] + bv);
      *(ushort4_t*)(hT + (bb*256 + hc)*4096 + n) = pk;   // h transposed [b][c][n]
    }
  }
}

// ---------------- Kernel C: flash attention ---------------------------------
// grid 512: batch = bid&7 (XCD-pins per-batch KV in one L2), qtile = bid>>3.
// 4 waves x 16 q-rows; KVBLK=128 (2 barriers per 128 keys).
// SWAPPED QK^T: s = mfma(K,Q) -> lane holds S[q=lane&15][16 keys] -> per-lane
// scalar m/li (2 shuffles, once), contiguous b64 P-writes. XOR-swizzled LDS
// (T2). V for tile t+1 reg-loaded during PV(t) (T14). setprio on PV (T5).
__global__ __launch_bounds__(256, 2) void attn_kernel(
    const ushort_t* __restrict__ fI, const ushort_t* __restrict__ gI,
    const ushort_t* __restrict__ hT, ushort_t* __restrict__ O){
  __shared__ ushort_t ldsV[256*128];       // [d][key] linear, XOR-swizzled (64 KB)
  __shared__ ushort_t ldsP[4][16*64];      // per-wave P [q][key], XOR-swizzled (8 KB)
  int bid = blockIdx.x, t = threadIdx.x;
  int b = bid & 7, qt = bid >> 3;
  int wv = t >> 6, l = t & 63, lrow = l & 15, lgrp = l >> 4;
  int q0 = qt*64 + wv*16;
  bf16x8 qa = *(const bf16x8*)(gI + ((long)b*4096 + q0 + lrow)*32 + lgrp*8);
  const ushort_t* hB = hT + (long)b*256*4096;
  const ushort_t* kp = fI + (long)b*4096*32 + lrow*32 + lgrp*8;
  f32x4 o[16];
#pragma unroll
  for (int i = 0; i < 16; ++i) o[i] = f32x4{0.f,0.f,0.f,0.f};
  float m = -1e30f, li = 0.f;              // per-lane state for q = lrow (log2 units)
  // V staging assignment: thread covers cols i*32+vcol, keys vks..vks+7 (+64)
  int vcol = t >> 3;                       // 0..31
  int vks  = (t & 7) * 8;                  // 0..56
  const ushort_t* vpb = hB + (long)vcol*4096 + vks;
  int swzV = (vcol & 7) << 3;              // LDS short-index XOR (=16B granule)
  int swzR = (lrow & 7) << 3;
  ushort_t* Pw = ldsP[wv];
  bf16x8 vreg[16];
#pragma unroll
  for (int i = 0; i < 8; ++i){
    vreg[2*i]   = *(const bf16x8*)(vpb + (long)i*32*4096);
    vreg[2*i+1] = *(const bf16x8*)(vpb + (long)i*32*4096 + 64);
  }
  for (int kt = 0; kt < 32; ++kt){
    int key0 = kt * 128;
    // K fragments for both subtiles (8 x b128 from L2), issued pre-barrier
    bf16x8 kb[8];
#pragma unroll
    for (int u = 0; u < 8; ++u) kb[u] = *(const bf16x8*)(kp + u*512);
    kp += 4096;
    __syncthreads();                       // B1: prev tile's V reads done
#pragma unroll
    for (int i = 0; i < 8; ++i){
      int base = (i*32 + vcol) << 7;
      *(bf16x8*)(ldsV + ((base + vks)      ^ swzV)) = vreg[2*i];
      *(bf16x8*)(ldsV + ((base + vks + 64) ^ swzV)) = vreg[2*i+1];
    }
    __syncthreads();                       // B2: V(t) visible
    // QK^T swapped: s01[u][rg] = S[q=lrow][key0 + u*16 + lgrp*4 + rg]
    f32x4 s01[8];
#pragma unroll
    for (int u = 0; u < 8; ++u) s01[u] = mfma16(kb[u], qa, f32x4{0.f,0.f,0.f,0.f});
    // prefetch next tile's V into regs (consumed at next B1; PV hides latency)
#pragma unroll
    for (int i = 0; i < 8; ++i){
      vreg[2*i]   = *(const bf16x8*)(vpb + (long)i*32*4096 + key0 + 128);
      vreg[2*i+1] = *(const bf16x8*)(vpb + (long)i*32*4096 + key0 + 192);
    }
    // row max over this lane's 32 keys, then across the 4 lgrp lanes
    float tm = -1e30f;
#pragma unroll
    for (int u = 0; u < 8; ++u)
#pragma unroll
      for (int rg = 0; rg < 4; ++rg) tm = fmaxf(tm, s01[u][rg]);
    tm = fmaxf(tm, __shfl_xor(tm, 16));
    tm = fmaxf(tm, __shfl_xor(tm, 32));
    if (__any(tm > m + 8.f)){              // defer-max (log2 units)
      float mn = fmaxf(m, tm);
      float sc = exp2f(m - mn);
      m = mn; li *= sc;
      float sc_o[4];
#pragma unroll
      for (int rg = 0; rg < 4; ++rg)
        sc_o[rg] = __shfl(sc, (l & 48) | ((l >> 2) & 12) | rg);
#pragma unroll
      for (int ct = 0; ct < 16; ++ct)
#pragma unroll
        for (int rg = 0; rg < 4; ++rg) o[ct][rg] *= sc_o[rg];
    }
    // per subtile: P pack -> LDS (b64, contiguous), then PV
#pragma unroll
    for (int sub = 0; sub < 2; ++sub){
#pragma unroll
      for (int st = 0; st < 4; ++st){
        int u = sub*4 + st;
        ushort4_t pk;
        float p0 = exp2f(s01[u][0] - m);
        float p1 = exp2f(s01[u][1] - m);
        float p2 = exp2f(s01[u][2] - m);
        float p3 = exp2f(s01[u][3] - m);
        li += (p0 + p1) + (p2 + p3);
        pk[0] = f2bf(p0); pk[1] = f2bf(p1); pk[2] = f2bf(p2); pk[3] = f2bf(p3);
        *(ushort4_t*)(Pw + (((lrow<<6) + (st<<4) + (lgrp<<2)) ^ swzR)) = pk;
      }
      asm volatile("s_waitcnt lgkmcnt(0)" ::: "memory");
      __builtin_amdgcn_sched_barrier(0);
      bf16x8 pa0 = *(const bf16x8*)(Pw + (((lrow<<6) + (lgrp<<3))      ^ swzR));
      bf16x8 pa1 = *(const bf16x8*)(Pw + (((lrow<<6) + (lgrp<<3) + 32) ^ swzR));
      __builtin_amdgcn_s_setprio(1);
#pragma unroll
      for (int ct = 0; ct < 16; ++ct){
        int base = ((ct*16 + lrow) << 7) + (sub << 6) + (lgrp << 3);
        bf16x8 b0 = *(const bf16x8*)(ldsV + ( base       ^ swzR));
        bf16x8 b1 = *(const bf16x8*)(ldsV + ((base + 32) ^ swzR));
        o[ct] = mfma16(pa0, b0, o[ct]);
        o[ct] = mfma16(pa1, b1, o[ct]);
      }
      __builtin_amdgcn_s_setprio(0);
    }
  }
  // li: reduce across the 4 lanes sharing q=lrow, then redistribute to D-layout
  li += __shfl_xor(li, 16);
  li += __shfl_xor(li, 32);
  float inv[4];
#pragma unroll
  for (int rg = 0; rg < 4; ++rg)
    inv[rg] = 1.0f / __shfl(li, (l & 48) | ((l >> 2) & 12) | rg);
  ushort_t* Ob = O + ((long)b*4096 + q0)*256;
#pragma unroll
  for (int ct = 0; ct < 16; ++ct){
    int col = ct*16 + lrow;
#pragma unroll
    for (int rg = 0; rg < 4; ++rg){
      int row = lgrp*4 + rg;
      Ob[(long)row*256 + col] = f2bf(o[ct][rg] * inv[rg]);
    }
  }
}

// ---------------- Kernel D: out = gamma*(O @ Wc_sn + bc) + x ---------------
__global__ __launch_bounds__(256) void out_kernel(
    const ushort_t* __restrict__ O, const ushort_t* __restrict__ WcT,
    const float* __restrict__ bc, const float* __restrict__ x,
    const float* __restrict__ gamma, float* __restrict__ out){
  int t = threadIdx.x;
  int wv = t >> 6, l = t & 63, lrow = l & 15, lgrp = l >> 4;
  long r0 = (long)blockIdx.x * 64 + wv * 16;
  f32x4 acc[16];
#pragma unroll
  for (int i = 0; i < 16; ++i) acc[i] = f32x4{0.f,0.f,0.f,0.f};
#pragma unroll
  for (int ks = 0; ks < 8; ++ks){
    int kk = ks*32 + lgrp*8;
    bf16x8 a = *(const bf16x8*)(O + (r0 + lrow)*256 + kk);
#pragma unroll
    for (int ct = 0; ct < 16; ++ct){
      bf16x8 bb = *(const bf16x8*)(WcT + (ct*16 + lrow)*256 + kk);
      acc[ct] = mfma16(a, bb, acc[ct]);
    }
  }
  float gm = gamma[0];
#pragma unroll
  for (int ct = 0; ct < 16; ++ct){
    int col = ct*16 + lrow;
    float bv = bc[col];
#pragma unroll
    for (int rg = 0; rg < 4; ++rg){
      long row = r0 + lgrp*4 + rg;
      out[row*256 + col] = gm*(acc[ct][rg] + bv) + x[row*256 + col];
    }
  }
}

extern "C" void kernel_launch(void* const* d_in, const int* in_sizes, int n_in,
                              void* d_out, int out_size, void* d_ws, size_t ws_size,
                              hipStream_t stream){
  (void)in_sizes; (void)n_in; (void)out_size; (void)ws_size;
  const float* x  = (const float*)d_in[0];
  const float* Wf = (const float*)d_in[1];
  const float* bf = (const float*)d_in[2];
  const float* uf = (const float*)d_in[3];
  const float* Wg = (const float*)d_in[4];
  const float* bg = (const float*)d_in[5];
  const float* ug = (const float*)d_in[6];
  const float* Wh = (const float*)d_in[7];
  const float* bh = (const float*)d_in[8];
  const float* uh = (const float*)d_in[9];
  const float* Wc = (const float*)d_in[10];
  const float* bc = (const float*)d_in[11];
  const float* uc = (const float*)d_in[12];
  const float* gamma = (const float*)d_in[13];
  float* out = (float*)d_out;

  char* w = (char*)d_ws;
  float*    inv_sigma = (float*)w;                                 // 16 B (pad 256)
  ushort_t* WallT = (ushort_t*)(w + 256);                          // 320*256*2 = 163840
  ushort_t* WcT   = (ushort_t*)(w + 256 + 163840);                 // 256*256*2 = 131072
  ushort_t* fW    = (ushort_t*)(w + 295168);                       // 8*4096*32*2 = 2097152
  ushort_t* gW    = (ushort_t*)(w + 295168 + 2097152);             // 2097152
  ushort_t* hTW   = (ushort_t*)(w + 295168 + 2*2097152);           // 8*256*4096*2 = 16777216
  ushort_t* OW    = (ushort_t*)(w + 295168 + 2*2097152 + 16777216);// 16777216

  hipLaunchKernelGGL(sigma_kernel, dim3(4),   dim3(256), 0, stream,
                     Wf, uf, Wg, ug, Wh, uh, Wc, uc, inv_sigma);
  hipLaunchKernelGGL(prep_weights, dim3(576), dim3(256), 0, stream,
                     Wf, Wg, Wh, Wc, inv_sigma, WallT, WcT);
  hipLaunchKernelGGL(fgh_kernel,   dim3(512), dim3(256), 0, stream,
                     x, WallT, bf, bg, bh, fW, gW, hTW);
  hipLaunchKernelGGL(attn_kernel,  dim3(512), dim3(256), 0, stream,
                     fW, gW, hTW, OW);
  hipLaunchKernelGGL(out_kernel,   dim3(512), dim3(256), 0, stream,
                     OW, WcT, bc, x, gamma, out);
}

// Round 4
// 220.264 us; speedup vs baseline: 1.4064x; 1.4064x over previous
//
#include <hip/hip_runtime.h>

typedef unsigned short ushort_t;
typedef __attribute__((ext_vector_type(8))) __bf16 bf16x8;
typedef __attribute__((ext_vector_type(4))) float f32x4;
typedef __attribute__((ext_vector_type(4))) ushort_t ushort4_t;

__device__ inline ushort_t f2bf(float f){
  __bf16 h = (__bf16)f;
  union { __bf16 h; ushort_t u; } v; v.h = h;
  return v.u;
}

__device__ inline f32x4 mfma16(bf16x8 a, bf16x8 b, f32x4 c){
  return __builtin_amdgcn_mfma_f32_16x16x32_bf16(a, b, c, 0, 0, 0);
}

// direct global->LDS, 16B per lane; LDS dest wave-uniform base + lane*16
#define GLDS16(gsrc, ldst) \
  __builtin_amdgcn_global_load_lds((const __attribute__((address_space(1))) unsigned int*)(gsrc), \
                                   (__attribute__((address_space(3))) unsigned int*)(ldst), 16, 0, 0)

// ---------------- Kernel A1: spectral norm sigma (one block per weight) ----
__global__ void sigma_kernel(const float* __restrict__ Wf, const float* __restrict__ uf,
                             const float* __restrict__ Wg, const float* __restrict__ ug,
                             const float* __restrict__ Wh, const float* __restrict__ uh,
                             const float* __restrict__ Wc, const float* __restrict__ uc,
                             float* __restrict__ inv_sigma){
  int w = blockIdx.x, t = threadIdx.x;
  const float *W, *u; int Cout;
  if      (w == 0){ W = Wf; u = uf; Cout = 32; }
  else if (w == 1){ W = Wg; u = ug; Cout = 32; }
  else if (w == 2){ W = Wh; u = uh; Cout = 256; }
  else            { W = Wc; u = uc; Cout = 256; }
  __shared__ float su[256], sv[256], red[256];
  su[t] = u[t];
  __syncthreads();
  float v = 0.f;
  if (t < Cout){
    for (int i = 0; i < 256; ++i) v += W[i*Cout + t] * su[i];
  }
  red[t] = (t < Cout) ? v*v : 0.f;
  __syncthreads();
  for (int s = 128; s > 0; s >>= 1){ if (t < s) red[t] += red[t+s]; __syncthreads(); }
  float nv = sqrtf(red[0]) + 1e-12f;
  __syncthreads();
  if (t < Cout) sv[t] = v / nv;
  __syncthreads();
  float wv = 0.f;
  for (int d = 0; d < Cout; ++d) wv += W[t*Cout + d] * sv[d];
  __syncthreads();
  red[t] = wv * wv;
  __syncthreads();
  for (int s = 128; s > 0; s >>= 1){ if (t < s) red[t] += red[t+s]; __syncthreads(); }
  if (t == 0){
    float ss2 = red[0];
    float sig = ss2 / (sqrtf(ss2) + 1e-12f);   // sigma = u_new . (W v)
    inv_sigma[w] = 1.0f / sig;
  }
}

// ---------------- Kernel A2: transpose + 1/sigma fold + bf16 cast ----------
__global__ void prep_weights(const float* __restrict__ Wf, const float* __restrict__ Wg,
                             const float* __restrict__ Wh, const float* __restrict__ Wc,
                             const float* __restrict__ inv_sigma,
                             ushort_t* __restrict__ WallT, ushort_t* __restrict__ WcT){
  int idx = blockIdx.x * 256 + threadIdx.x;   // 0 .. 147455
  if (idx < 81920){                            // WallT[c][k], c in [0,320)
    int c = idx >> 8, k = idx & 255;
    float val, is;
    if (c < 32)      { val = Wf[k*32  + c      ]; is = inv_sigma[0]; }
    else if (c < 64) { val = Wg[k*32  + (c-32) ]; is = inv_sigma[1]; }
    else             { val = Wh[k*256 + (c-64) ]; is = inv_sigma[2]; }
    WallT[idx] = f2bf(val * is);
  } else {
    int j = idx - 81920; int c = j >> 8, k = j & 255;
    WcT[j] = f2bf(Wc[k*256 + c] * inv_sigma[3]);
  }
}

// ---------------- Kernel B: f,g,h = x @ [Wf|Wg|Wh]_sn + bias ---------------
// g (queries) pre-scaled by log2(e) so attention softmax can use exp2.
__global__ __launch_bounds__(256) void fgh_kernel(
    const float* __restrict__ x, const ushort_t* __restrict__ WallT,
    const float* __restrict__ bf, const float* __restrict__ bg, const float* __restrict__ bh,
    ushort_t* __restrict__ fO, ushort_t* __restrict__ gO, ushort_t* __restrict__ hT){
  int t = threadIdx.x;
  int wv = t >> 6, l = t & 63, lrow = l & 15, lgrp = l >> 4;
  long r0 = (long)blockIdx.x * 64 + wv * 16;
  const float* xrow = x + (r0 + lrow) * 256;
  f32x4 acc[20];
#pragma unroll
  for (int i = 0; i < 20; ++i) acc[i] = f32x4{0.f,0.f,0.f,0.f};
#pragma unroll
  for (int ks = 0; ks < 8; ++ks){
    int kk = ks*32 + lgrp*8;
    f32x4 xa = *(const f32x4*)(xrow + kk);
    f32x4 xb = *(const f32x4*)(xrow + kk + 4);
    union { __bf16 h[8]; bf16x8 v; } A;
#pragma unroll
    for (int j = 0; j < 4; ++j){ A.h[j] = (__bf16)xa[j]; A.h[4+j] = (__bf16)xb[j]; }
#pragma unroll
    for (int ct = 0; ct < 20; ++ct){
      bf16x8 bb = *(const bf16x8*)(WallT + (ct*16 + lrow)*256 + kk);
      acc[ct] = mfma16(A.v, bb, acc[ct]);
    }
  }
#pragma unroll
  for (int ct = 0; ct < 20; ++ct){
    int col = ct*16 + lrow;
    long rowb = r0 + lgrp*4;
    if (col < 32){
      float bv = bf[col];
#pragma unroll
      for (int rg = 0; rg < 4; ++rg) fO[(rowb+rg)*32 + col] = f2bf(acc[ct][rg] + bv);
    } else if (col < 64){
      float bv = bg[col-32];
#pragma unroll
      for (int rg = 0; rg < 4; ++rg)
        gO[(rowb+rg)*32 + (col-32)] = f2bf((acc[ct][rg] + bv) * 1.44269504f);
    } else {
      int hc = col - 64;
      float bv = bh[hc];
      long bb = rowb >> 12, n = rowb & 4095;
      ushort4_t pk;
#pragma unroll
      for (int rg = 0; rg < 4; ++rg) pk[rg] = f2bf(acc[ct][rg] + bv);
      *(ushort4_t*)(hT + (bb*256 + hc)*4096 + n) = pk;   // h transposed [b][c][n]
    }
  }
}

// ---------------- Kernel C: flash attention, SPLIT-K ------------------------
// grid 1024: b = bid&7 (XCD L2 pin), qt = (bid>>3)>>1, khalf = (bid>>3)&1.
// Each block: 64 q-rows x 2048 keys -> unnormalized partial o (bf16) + m,li.
// KVBLK=64; V staged via global_load_lds (linear dest, pre-swizzled source,
// XOR-swizzled read). Swapped QK^T -> per-lane softmax. 40KB LDS, <=128 VGPR
// -> 4 blocks/CU (vs round-2's grid-capped 2).
__global__ __launch_bounds__(256, 4) void attn_kernel(
    const ushort_t* __restrict__ fI, const ushort_t* __restrict__ gI,
    const ushort_t* __restrict__ hT,
    ushort_t* __restrict__ oP, float* __restrict__ mP, float* __restrict__ liP){
  __shared__ ushort_t ldsV[256*64];        // 32 KB: LDS[d*64+j] = V[d][j ^ ((d&7)*8)]
  __shared__ ushort_t ldsP[4][16*64];      // 8 KB, per-wave P, XOR-swizzled
  int bid = blockIdx.x, t = threadIdx.x;
  int b = bid & 7, rest = bid >> 3, qt = rest >> 1, kh = rest & 1;
  int wv = t >> 6, l = t & 63, lrow = l & 15, lgrp = l >> 4;
  int q0 = qt*64 + wv*16;
  long key_base = (long)kh * 2048;
  bf16x8 qa = *(const bf16x8*)(gI + ((long)b*4096 + q0 + lrow)*32 + lgrp*8);
  const ushort_t* hB = hT + (long)b*256*4096;
  const ushort_t* kp = fI + (long)b*4096*32 + key_base*32 + lrow*32 + lgrp*8;
  // per-lane pre-swizzled V source: d = wv*64 + i*8 + (l>>3), k ^= (d&7)*8
  const ushort_t* vsrc = hB + (long)(wv*64 + (l>>3))*4096 + key_base
                            + (((l & 7) ^ (l >> 3)) << 3);
  ushort_t* vdst = ldsV + wv*4096;         // + i*512 per issue (wave-uniform)
  f32x4 o[16];
#pragma unroll
  for (int i = 0; i < 16; ++i) o[i] = f32x4{0.f,0.f,0.f,0.f};
  float m = -1e30f, li = 0.f;              // per-lane state for q=lrow (log2 units)
  int swzR = (lrow & 7) << 3;
  ushort_t* Pw = ldsP[wv];
  for (int kt = 0; kt < 32; ++kt){
    __syncthreads();                       // prev tile's ldsV reads complete
    // K fragments (L2-resident); compiler's counted waits leave V loads in flight
    bf16x8 kb0 = *(const bf16x8*)(kp);
    bf16x8 kb1 = *(const bf16x8*)(kp + 512);
    bf16x8 kb2 = *(const bf16x8*)(kp + 1024);
    bf16x8 kb3 = *(const bf16x8*)(kp + 1536);
    kp += 2048;
    // V tile kt: 8 direct global->LDS issues per wave (zero staging VGPRs)
    const ushort_t* vs = vsrc + kt*64;
#pragma unroll
    for (int i = 0; i < 8; ++i)
      GLDS16(vs + i*32768, vdst + i*512);
    // swapped QK^T: s[u] holds S[key = u*16+lgrp*4+rg][q = lrow]
    f32x4 s0 = mfma16(kb0, qa, f32x4{0.f,0.f,0.f,0.f});
    f32x4 s1 = mfma16(kb1, qa, f32x4{0.f,0.f,0.f,0.f});
    f32x4 s2 = mfma16(kb2, qa, f32x4{0.f,0.f,0.f,0.f});
    f32x4 s3 = mfma16(kb3, qa, f32x4{0.f,0.f,0.f,0.f});
    // row max over this lane's 16 keys, then across the 4 lanes sharing q
    float tm = fmaxf(fmaxf(fmaxf(s0[0], s0[1]), fmaxf(s0[2], s0[3])),
               fmaxf(fmaxf(s1[0], s1[1]), fmaxf(s1[2], s1[3])));
    tm = fmaxf(tm, fmaxf(fmaxf(fmaxf(s2[0], s2[1]), fmaxf(s2[2], s2[3])),
                         fmaxf(fmaxf(s3[0], s3[1]), fmaxf(s3[2], s3[3]))));
    tm = fmaxf(tm, __shfl_xor(tm, 16));
    tm = fmaxf(tm, __shfl_xor(tm, 32));
    if (__any(tm > m + 8.f)){              // defer-max (T13, log2 units)
      float mn = fmaxf(m, tm);
      float sc = exp2f(m - mn);
      m = mn; li *= sc;
      float sc_o[4];
#pragma unroll
      for (int rg = 0; rg < 4; ++rg)
        sc_o[rg] = __shfl(sc, (l & 48) | ((l >> 2) & 12) | rg);
#pragma unroll
      for (int ct = 0; ct < 16; ++ct)
#pragma unroll
        for (int rg = 0; rg < 4; ++rg) o[ct][rg] *= sc_o[rg];
    }
    // P = exp2(s - m) -> pack b64 to swizzled LDS; accumulate li
#pragma unroll
    for (int st = 0; st < 4; ++st){
      f32x4 sv = (st == 0) ? s0 : (st == 1) ? s1 : (st == 2) ? s2 : s3;
      float p0 = exp2f(sv[0] - m);
      float p1 = exp2f(sv[1] - m);
      float p2 = exp2f(sv[2] - m);
      float p3 = exp2f(sv[3] - m);
      li += (p0 + p1) + (p2 + p3);
      ushort4_t pk;
      pk[0] = f2bf(p0); pk[1] = f2bf(p1); pk[2] = f2bf(p2); pk[3] = f2bf(p3);
      *(ushort4_t*)(Pw + (((lrow << 6) + (st << 4) + (lgrp << 2)) ^ swzR)) = pk;
    }
    asm volatile("s_waitcnt lgkmcnt(0)" ::: "memory");
    __builtin_amdgcn_sched_barrier(0);
    bf16x8 pa0 = *(const bf16x8*)(Pw + (((lrow << 6) + (lgrp << 3))      ^ swzR));
    bf16x8 pa1 = *(const bf16x8*)(Pw + (((lrow << 6) + (lgrp << 3) + 32) ^ swzR));
    asm volatile("s_waitcnt vmcnt(0)" ::: "memory");   // V tile landed in LDS
    __syncthreads();                       // all waves' V visible
    __builtin_amdgcn_s_setprio(1);
#pragma unroll
    for (int ct = 0; ct < 16; ++ct){
      int base = (ct*16 + lrow) << 6;
      bf16x8 b0 = *(const bf16x8*)(ldsV + base + (((lgrp << 3))      ^ swzR));
      bf16x8 b1 = *(const bf16x8*)(ldsV + base + (((lgrp << 3) + 32) ^ swzR));
      o[ct] = mfma16(pa0, b0, o[ct]);
      o[ct] = mfma16(pa1, b1, o[ct]);
    }
    __builtin_amdgcn_s_setprio(0);
  }
  // reduce li across the 4 lanes sharing q=lrow; store partials
  li += __shfl_xor(li, 16);
  li += __shfl_xor(li, 32);
  long rbase = (long)b*4096 + q0;
  ushort_t* Ob = oP + ((long)kh*32768 + rbase)*256;
#pragma unroll
  for (int ct = 0; ct < 16; ++ct){
    int col = ct*16 + lrow;
#pragma unroll
    for (int rg = 0; rg < 4; ++rg){
      int row = lgrp*4 + rg;
      Ob[(long)row*256 + col] = f2bf(o[ct][rg]);   // unnormalized partial
    }
  }
  if (l < 16){
    mP [kh*32768 + rbase + lrow] = m;
    liP[kh*32768 + rbase + lrow] = li;
  }
}

// ---------------- Kernel D: combine split-K + out = gamma*(O@Wc + bc) + x --
__global__ __launch_bounds__(256) void out_kernel(
    const ushort_t* __restrict__ oP, const float* __restrict__ mP,
    const float* __restrict__ liP, const ushort_t* __restrict__ WcT,
    const float* __restrict__ bc, const float* __restrict__ x,
    const float* __restrict__ gamma, float* __restrict__ out){
  int t = threadIdx.x;
  int wv = t >> 6, l = t & 63, lrow = l & 15, lgrp = l >> 4;
  long r0 = (long)blockIdx.x * 64 + wv * 16;
  long r = r0 + lrow;                       // this lane's A row (fixed)
  float m1 = mP[r],  m2 = mP[32768 + r];
  float li1 = liP[r], li2 = liP[32768 + r];
  float mm  = fmaxf(m1, m2);
  float sc1 = exp2f(m1 - mm), sc2 = exp2f(m2 - mm);
  float inv = 1.0f / (li1*sc1 + li2*sc2);
  float w1 = sc1 * inv, w2 = sc2 * inv;
  const ushort_t* o1 = oP + r*256;
  const ushort_t* o2 = oP + 32768L*256 + r*256;
  f32x4 acc[16];
#pragma unroll
  for (int i = 0; i < 16; ++i) acc[i] = f32x4{0.f,0.f,0.f,0.f};
#pragma unroll
  for (int ks = 0; ks < 8; ++ks){
    int kk = ks*32 + lgrp*8;
    bf16x8 a1 = *(const bf16x8*)(o1 + kk);
    bf16x8 a2 = *(const bf16x8*)(o2 + kk);
    union { __bf16 h[8]; bf16x8 v; } A;
#pragma unroll
    for (int j = 0; j < 8; ++j)
      A.h[j] = (__bf16)((float)a1[j]*w1 + (float)a2[j]*w2);
#pragma unroll
    for (int ct = 0; ct < 16; ++ct){
      bf16x8 bb = *(const bf16x8*)(WcT + (ct*16 + lrow)*256 + kk);
      acc[ct] = mfma16(A.v, bb, acc[ct]);
    }
  }
  float gm = gamma[0];
#pragma unroll
  for (int ct = 0; ct < 16; ++ct){
    int col = ct*16 + lrow;
    float bv = bc[col];
#pragma unroll
    for (int rg = 0; rg < 4; ++rg){
      long row = r0 + lgrp*4 + rg;
      out[row*256 + col] = gm*(acc[ct][rg] + bv) + x[row*256 + col];
    }
  }
}

extern "C" void kernel_launch(void* const* d_in, const int* in_sizes, int n_in,
                              void* d_out, int out_size, void* d_ws, size_t ws_size,
                              hipStream_t stream){
  (void)in_sizes; (void)n_in; (void)out_size; (void)ws_size;
  const float* x  = (const float*)d_in[0];
  const float* Wf = (const float*)d_in[1];
  const float* bf = (const float*)d_in[2];
  const float* uf = (const float*)d_in[3];
  const float* Wg = (const float*)d_in[4];
  const float* bg = (const float*)d_in[5];
  const float* ug = (const float*)d_in[6];
  const float* Wh = (const float*)d_in[7];
  const float* bh = (const float*)d_in[8];
  const float* uh = (const float*)d_in[9];
  const float* Wc = (const float*)d_in[10];
  const float* bc = (const float*)d_in[11];
  const float* uc = (const float*)d_in[12];
  const float* gamma = (const float*)d_in[13];
  float* out = (float*)d_out;

  char* w = (char*)d_ws;
  float*    inv_sigma = (float*)w;                         // @0,     256 B
  ushort_t* WallT = (ushort_t*)(w + 256);                  // 163840
  ushort_t* WcT   = (ushort_t*)(w + 164096);               // 131072
  ushort_t* fW    = (ushort_t*)(w + 295168);               // 2 MB
  ushort_t* gW    = (ushort_t*)(w + 2392320);              // 2 MB
  ushort_t* hTW   = (ushort_t*)(w + 4489472);              // 16 MB
  ushort_t* oPW   = (ushort_t*)(w + 21266688);             // 32 MB (2 x 8x4096x256 bf16)
  float*    mPW   = (float*)   (w + 54821120);             // 256 KB
  float*    liPW  = (float*)   (w + 55083264);             // 256 KB  -> total ~55.3 MB

  hipLaunchKernelGGL(sigma_kernel, dim3(4),    dim3(256), 0, stream,
                     Wf, uf, Wg, ug, Wh, uh, Wc, uc, inv_sigma);
  hipLaunchKernelGGL(prep_weights, dim3(576),  dim3(256), 0, stream,
                     Wf, Wg, Wh, Wc, inv_sigma, WallT, WcT);
  hipLaunchKernelGGL(fgh_kernel,   dim3(512),  dim3(256), 0, stream,
                     x, WallT, bf, bg, bh, fW, gW, hTW);
  hipLaunchKernelGGL(attn_kernel,  dim3(1024), dim3(256), 0, stream,
                     fW, gW, hTW, oPW, mPW, liPW);
  hipLaunchKernelGGL(out_kernel,   dim3(512),  dim3(256), 0, stream,
                     oPW, mPW, liPW, WcT, bc, x, gamma, out);
}

// Round 5
// 219.361 us; speedup vs baseline: 1.4122x; 1.0041x over previous
//
#include <hip/hip_runtime.h>

typedef unsigned short ushort_t;
typedef __attribute__((ext_vector_type(8))) __bf16 bf16x8;
typedef __attribute__((ext_vector_type(4))) float f32x4;
typedef __attribute__((ext_vector_type(4))) ushort_t ushort4_t;

__device__ inline ushort_t f2bf(float f){
  __bf16 h = (__bf16)f;
  union { __bf16 h; ushort_t u; } v; v.h = h;
  return v.u;
}

__device__ inline f32x4 mfma16(bf16x8 a, bf16x8 b, f32x4 c){
  return __builtin_amdgcn_mfma_f32_16x16x32_bf16(a, b, c, 0, 0, 0);
}

// direct global->LDS, 16B per lane; LDS dest wave-uniform base + lane*16
#define GLDS16(gsrc, ldst) \
  __builtin_amdgcn_global_load_lds((const __attribute__((address_space(1))) unsigned int*)(gsrc), \
                                   (__attribute__((address_space(3))) unsigned int*)(ldst), 16, 0, 0)

// ---------------- Kernel A1: spectral norm sigma (one block per weight) ----
__global__ void sigma_kernel(const float* __restrict__ Wf, const float* __restrict__ uf,
                             const float* __restrict__ Wg, const float* __restrict__ ug,
                             const float* __restrict__ Wh, const float* __restrict__ uh,
                             const float* __restrict__ Wc, const float* __restrict__ uc,
                             float* __restrict__ inv_sigma){
  int w = blockIdx.x, t = threadIdx.x;
  const float *W, *u; int Cout;
  if      (w == 0){ W = Wf; u = uf; Cout = 32; }
  else if (w == 1){ W = Wg; u = ug; Cout = 32; }
  else if (w == 2){ W = Wh; u = uh; Cout = 256; }
  else            { W = Wc; u = uc; Cout = 256; }
  __shared__ float su[256], sv[256], red[256];
  su[t] = u[t];
  __syncthreads();
  float v = 0.f;
  if (t < Cout){
    for (int i = 0; i < 256; ++i) v += W[i*Cout + t] * su[i];
  }
  red[t] = (t < Cout) ? v*v : 0.f;
  __syncthreads();
  for (int s = 128; s > 0; s >>= 1){ if (t < s) red[t] += red[t+s]; __syncthreads(); }
  float nv = sqrtf(red[0]) + 1e-12f;
  __syncthreads();
  if (t < Cout) sv[t] = v / nv;
  __syncthreads();
  float wv = 0.f;
  for (int d = 0; d < Cout; ++d) wv += W[t*Cout + d] * sv[d];
  __syncthreads();
  red[t] = wv * wv;
  __syncthreads();
  for (int s = 128; s > 0; s >>= 1){ if (t < s) red[t] += red[t+s]; __syncthreads(); }
  if (t == 0){
    float ss2 = red[0];
    float sig = ss2 / (sqrtf(ss2) + 1e-12f);   // sigma = u_new . (W v)
    inv_sigma[w] = 1.0f / sig;
  }
}

// ---------------- Kernel A2: transpose + 1/sigma fold + bf16 cast ----------
__global__ void prep_weights(const float* __restrict__ Wf, const float* __restrict__ Wg,
                             const float* __restrict__ Wh, const float* __restrict__ Wc,
                             const float* __restrict__ inv_sigma,
                             ushort_t* __restrict__ WallT, ushort_t* __restrict__ WcT){
  int idx = blockIdx.x * 256 + threadIdx.x;   // 0 .. 147455
  if (idx < 81920){                            // WallT[c][k], c in [0,320)
    int c = idx >> 8, k = idx & 255;
    float val, is;
    if (c < 32)      { val = Wf[k*32  + c      ]; is = inv_sigma[0]; }
    else if (c < 64) { val = Wg[k*32  + (c-32) ]; is = inv_sigma[1]; }
    else             { val = Wh[k*256 + (c-64) ]; is = inv_sigma[2]; }
    WallT[idx] = f2bf(val * is);
  } else {
    int j = idx - 81920; int c = j >> 8, k = j & 255;
    WcT[j] = f2bf(Wc[k*256 + c] * inv_sigma[3]);
  }
}

// ---------------- Kernel B: f,g,h = x @ [Wf|Wg|Wh]_sn + bias ---------------
// x staged per-wave via global_load_lds (coalesced 1KB/instr, pre-swizzled
// source + XOR-swizzled reads, rule-21 pair). Wave-private region: vmcnt only,
// no barriers. g pre-scaled by log2(e).
__global__ __launch_bounds__(256) void fgh_kernel(
    const float* __restrict__ x, const ushort_t* __restrict__ WallT,
    const float* __restrict__ bf, const float* __restrict__ bg, const float* __restrict__ bh,
    ushort_t* __restrict__ fO, ushort_t* __restrict__ gO, ushort_t* __restrict__ hT){
  __shared__ __attribute__((aligned(16))) char ldsX[4][16384];  // 16 rows x 1KB per wave
  int t = threadIdx.x;
  int wv = t >> 6, l = t & 63, lrow = l & 15, lgrp = l >> 4;
  long r0 = (long)blockIdx.x * 64 + wv * 16;
  // stage 16 x-rows; one GLDS instr = one full row (64 lanes x 16B)
  char* ldsW = ldsX[wv];
#pragma unroll
  for (int rloc = 0; rloc < 16; ++rloc){
    const char* src = (const char*)(x + (r0 + rloc)*256)
                    + ((l*16) ^ ((rloc & 7) << 4));
    GLDS16(src, ldsW + rloc*1024);
  }
  asm volatile("s_waitcnt vmcnt(0)" ::: "memory");
  const char* xrow = ldsW + lrow*1024;
  int swzX = (lrow & 7) << 4;
  f32x4 acc[20];
#pragma unroll
  for (int i = 0; i < 20; ++i) acc[i] = f32x4{0.f,0.f,0.f,0.f};
#pragma unroll
  for (int ks = 0; ks < 8; ++ks){
    int bb = ks*128 + lgrp*32;
    f32x4 xa = *(const f32x4*)(xrow + ( bb       ^ swzX));
    f32x4 xb = *(const f32x4*)(xrow + ((bb + 16) ^ swzX));
    union { __bf16 h[8]; bf16x8 v; } A;
#pragma unroll
    for (int j = 0; j < 4; ++j){ A.h[j] = (__bf16)xa[j]; A.h[4+j] = (__bf16)xb[j]; }
    int kk = ks*32 + lgrp*8;
#pragma unroll
    for (int ct = 0; ct < 20; ++ct){
      bf16x8 bbv = *(const bf16x8*)(WallT + (ct*16 + lrow)*256 + kk);
      acc[ct] = mfma16(A.v, bbv, acc[ct]);
    }
  }
#pragma unroll
  for (int ct = 0; ct < 20; ++ct){
    int col = ct*16 + lrow;
    long rowb = r0 + lgrp*4;
    if (col < 32){
      float bv = bf[col];
#pragma unroll
      for (int rg = 0; rg < 4; ++rg) fO[(rowb+rg)*32 + col] = f2bf(acc[ct][rg] + bv);
    } else if (col < 64){
      float bv = bg[col-32];
#pragma unroll
      for (int rg = 0; rg < 4; ++rg)
        gO[(rowb+rg)*32 + (col-32)] = f2bf((acc[ct][rg] + bv) * 1.44269504f);
    } else {
      int hc = col - 64;
      float bv = bh[hc];
      long bb2 = rowb >> 12, n = rowb & 4095;
      ushort4_t pk;
#pragma unroll
      for (int rg = 0; rg < 4; ++rg) pk[rg] = f2bf(acc[ct][rg] + bv);
      *(ushort4_t*)(hT + (bb2*256 + hc)*4096 + n) = pk;   // h transposed [b][c][n]
    }
  }
}

// ---------------- Kernel C: flash attention, SPLIT-K (unchanged, proven) ----
__global__ __launch_bounds__(256, 4) void attn_kernel(
    const ushort_t* __restrict__ fI, const ushort_t* __restrict__ gI,
    const ushort_t* __restrict__ hT,
    ushort_t* __restrict__ oP, float* __restrict__ mP, float* __restrict__ liP){
  __shared__ ushort_t ldsV[256*64];        // 32 KB: LDS[d*64+j] = V[d][j ^ ((d&7)*8)]
  __shared__ ushort_t ldsP[4][16*64];      // 8 KB, per-wave P, XOR-swizzled
  int bid = blockIdx.x, t = threadIdx.x;
  int b = bid & 7, rest = bid >> 3, qt = rest >> 1, kh = rest & 1;
  int wv = t >> 6, l = t & 63, lrow = l & 15, lgrp = l >> 4;
  int q0 = qt*64 + wv*16;
  long key_base = (long)kh * 2048;
  bf16x8 qa = *(const bf16x8*)(gI + ((long)b*4096 + q0 + lrow)*32 + lgrp*8);
  const ushort_t* hB = hT + (long)b*256*4096;
  const ushort_t* kp = fI + (long)b*4096*32 + key_base*32 + lrow*32 + lgrp*8;
  const ushort_t* vsrc = hB + (long)(wv*64 + (l>>3))*4096 + key_base
                            + (((l & 7) ^ (l >> 3)) << 3);
  ushort_t* vdst = ldsV + wv*4096;
  f32x4 o[16];
#pragma unroll
  for (int i = 0; i < 16; ++i) o[i] = f32x4{0.f,0.f,0.f,0.f};
  float m = -1e30f, li = 0.f;
  int swzR = (lrow & 7) << 3;
  ushort_t* Pw = ldsP[wv];
  for (int kt = 0; kt < 32; ++kt){
    __syncthreads();
    bf16x8 kb0 = *(const bf16x8*)(kp);
    bf16x8 kb1 = *(const bf16x8*)(kp + 512);
    bf16x8 kb2 = *(const bf16x8*)(kp + 1024);
    bf16x8 kb3 = *(const bf16x8*)(kp + 1536);
    kp += 2048;
    const ushort_t* vs = vsrc + kt*64;
#pragma unroll
    for (int i = 0; i < 8; ++i)
      GLDS16(vs + i*32768, vdst + i*512);
    f32x4 s0 = mfma16(kb0, qa, f32x4{0.f,0.f,0.f,0.f});
    f32x4 s1 = mfma16(kb1, qa, f32x4{0.f,0.f,0.f,0.f});
    f32x4 s2 = mfma16(kb2, qa, f32x4{0.f,0.f,0.f,0.f});
    f32x4 s3 = mfma16(kb3, qa, f32x4{0.f,0.f,0.f,0.f});
    float tm = fmaxf(fmaxf(fmaxf(s0[0], s0[1]), fmaxf(s0[2], s0[3])),
               fmaxf(fmaxf(s1[0], s1[1]), fmaxf(s1[2], s1[3])));
    tm = fmaxf(tm, fmaxf(fmaxf(fmaxf(s2[0], s2[1]), fmaxf(s2[2], s2[3])),
                         fmaxf(fmaxf(s3[0], s3[1]), fmaxf(s3[2], s3[3]))));
    tm = fmaxf(tm, __shfl_xor(tm, 16));
    tm = fmaxf(tm, __shfl_xor(tm, 32));
    if (__any(tm > m + 8.f)){              // defer-max (T13, log2 units)
      float mn = fmaxf(m, tm);
      float sc = exp2f(m - mn);
      m = mn; li *= sc;
      float sc_o[4];
#pragma unroll
      for (int rg = 0; rg < 4; ++rg)
        sc_o[rg] = __shfl(sc, (l & 48) | ((l >> 2) & 12) | rg);
#pragma unroll
      for (int ct = 0; ct < 16; ++ct)
#pragma unroll
        for (int rg = 0; rg < 4; ++rg) o[ct][rg] *= sc_o[rg];
    }
#pragma unroll
    for (int st = 0; st < 4; ++st){
      f32x4 sv = (st == 0) ? s0 : (st == 1) ? s1 : (st == 2) ? s2 : s3;
      float p0 = exp2f(sv[0] - m);
      float p1 = exp2f(sv[1] - m);
      float p2 = exp2f(sv[2] - m);
      float p3 = exp2f(sv[3] - m);
      li += (p0 + p1) + (p2 + p3);
      ushort4_t pk;
      pk[0] = f2bf(p0); pk[1] = f2bf(p1); pk[2] = f2bf(p2); pk[3] = f2bf(p3);
      *(ushort4_t*)(Pw + (((lrow << 6) + (st << 4) + (lgrp << 2)) ^ swzR)) = pk;
    }
    asm volatile("s_waitcnt lgkmcnt(0)" ::: "memory");
    __builtin_amdgcn_sched_barrier(0);
    bf16x8 pa0 = *(const bf16x8*)(Pw + (((lrow << 6) + (lgrp << 3))      ^ swzR));
    bf16x8 pa1 = *(const bf16x8*)(Pw + (((lrow << 6) + (lgrp << 3) + 32) ^ swzR));
    asm volatile("s_waitcnt vmcnt(0)" ::: "memory");
    __syncthreads();
    __builtin_amdgcn_s_setprio(1);
#pragma unroll
    for (int ct = 0; ct < 16; ++ct){
      int base = (ct*16 + lrow) << 6;
      bf16x8 b0 = *(const bf16x8*)(ldsV + base + (((lgrp << 3))      ^ swzR));
      bf16x8 b1 = *(const bf16x8*)(ldsV + base + (((lgrp << 3) + 32) ^ swzR));
      o[ct] = mfma16(pa0, b0, o[ct]);
      o[ct] = mfma16(pa1, b1, o[ct]);
    }
    __builtin_amdgcn_s_setprio(0);
  }
  li += __shfl_xor(li, 16);
  li += __shfl_xor(li, 32);
  long rbase = (long)b*4096 + q0;
  ushort_t* Ob = oP + ((long)kh*32768 + rbase)*256;
#pragma unroll
  for (int ct = 0; ct < 16; ++ct){
    int col = ct*16 + lrow;
#pragma unroll
    for (int rg = 0; rg < 4; ++rg){
      int row = lgrp*4 + rg;
      Ob[(long)row*256 + col] = f2bf(o[ct][rg]);   // unnormalized partial
    }
  }
  if (l < 16){
    mP [kh*32768 + rbase + lrow] = m;
    liP[kh*32768 + rbase + lrow] = li;
  }
}

// ---------------- Kernel D: combine split-K + out = gamma*(O@Wc + bc) + x --
// oP halves staged per-wave via global_load_lds (2 rows per instr), swizzled.
__global__ __launch_bounds__(256) void out_kernel(
    const ushort_t* __restrict__ oP, const float* __restrict__ mP,
    const float* __restrict__ liP, const ushort_t* __restrict__ WcT,
    const float* __restrict__ bc, const float* __restrict__ x,
    const float* __restrict__ gamma, float* __restrict__ out){
  __shared__ __attribute__((aligned(16))) char ldsO[4][16384]; // per wave: o1 8KB | o2 8KB
  int t = threadIdx.x;
  int wv = t >> 6, l = t & 63, lrow = l & 15, lgrp = l >> 4;
  long r0 = (long)blockIdx.x * 64 + wv * 16;
  char* ldsW = ldsO[wv];
  // stage 16 rows of each oP half; one GLDS = 2 rows (512B each)
#pragma unroll
  for (int i = 0; i < 8; ++i){
    int rloc = 2*i + (l >> 5);
    int soff = ((l & 31)*16) ^ ((rloc & 7) << 4);
    GLDS16((const char*)(oP + (r0 + rloc)*256) + soff,            ldsW + i*1024);
    GLDS16((const char*)(oP + (32768L + r0 + rloc)*256) + soff,   ldsW + 8192 + i*1024);
  }
  long r = r0 + lrow;                       // this lane's A row (fixed)
  float m1 = mP[r],  m2 = mP[32768 + r];
  float li1 = liP[r], li2 = liP[32768 + r];
  float mm  = fmaxf(m1, m2);
  float sc1 = exp2f(m1 - mm), sc2 = exp2f(m2 - mm);
  float inv = 1.0f / (li1*sc1 + li2*sc2);
  float w1 = sc1 * inv, w2 = sc2 * inv;
  asm volatile("s_waitcnt vmcnt(0)" ::: "memory");
  const char* orow = ldsW + lrow*512;
  int swzO = (lrow & 7) << 4;
  f32x4 acc[16];
#pragma unroll
  for (int i = 0; i < 16; ++i) acc[i] = f32x4{0.f,0.f,0.f,0.f};
#pragma unroll
  for (int ks = 0; ks < 8; ++ks){
    int bb = (ks*64 + lgrp*16) ^ swzO;
    bf16x8 a1 = *(const bf16x8*)(orow + bb);
    bf16x8 a2 = *(const bf16x8*)(orow + 8192 + bb);
    union { __bf16 h[8]; bf16x8 v; } A;
#pragma unroll
    for (int j = 0; j < 8; ++j)
      A.h[j] = (__bf16)((float)a1[j]*w1 + (float)a2[j]*w2);
    int kk = ks*32 + lgrp*8;
#pragma unroll
    for (int ct = 0; ct < 16; ++ct){
      bf16x8 bbv = *(const bf16x8*)(WcT + (ct*16 + lrow)*256 + kk);
      acc[ct] = mfma16(A.v, bbv, acc[ct]);
    }
  }
  float gm = gamma[0];
#pragma unroll
  for (int ct = 0; ct < 16; ++ct){
    int col = ct*16 + lrow;
    float bv = bc[col];
#pragma unroll
    for (int rg = 0; rg < 4; ++rg){
      long row = r0 + lgrp*4 + rg;
      out[row*256 + col] = gm*(acc[ct][rg] + bv) + x[row*256 + col];
    }
  }
}

extern "C" void kernel_launch(void* const* d_in, const int* in_sizes, int n_in,
                              void* d_out, int out_size, void* d_ws, size_t ws_size,
                              hipStream_t stream){
  (void)in_sizes; (void)n_in; (void)out_size; (void)ws_size;
  const float* x  = (const float*)d_in[0];
  const float* Wf = (const float*)d_in[1];
  const float* bf = (const float*)d_in[2];
  const float* uf = (const float*)d_in[3];
  const float* Wg = (const float*)d_in[4];
  const float* bg = (const float*)d_in[5];
  const float* ug = (const float*)d_in[6];
  const float* Wh = (const float*)d_in[7];
  const float* bh = (const float*)d_in[8];
  const float* uh = (const float*)d_in[9];
  const float* Wc = (const float*)d_in[10];
  const float* bc = (const float*)d_in[11];
  const float* uc = (const float*)d_in[12];
  const float* gamma = (const float*)d_in[13];
  float* out = (float*)d_out;

  char* w = (char*)d_ws;
  float*    inv_sigma = (float*)w;                         // @0,     256 B
  ushort_t* WallT = (ushort_t*)(w + 256);                  // 163840
  ushort_t* WcT   = (ushort_t*)(w + 164096);               // 131072
  ushort_t* fW    = (ushort_t*)(w + 295168);               // 2 MB
  ushort_t* gW    = (ushort_t*)(w + 2392320);              // 2 MB
  ushort_t* hTW   = (ushort_t*)(w + 4489472);              // 16 MB
  ushort_t* oPW   = (ushort_t*)(w + 21266688);             // 32 MB (2 x 8x4096x256 bf16)
  float*    mPW   = (float*)   (w + 54821120);             // 256 KB
  float*    liPW  = (float*)   (w + 55083264);             // 256 KB  -> total ~55.3 MB

  hipLaunchKernelGGL(sigma_kernel, dim3(4),    dim3(256), 0, stream,
                     Wf, uf, Wg, ug, Wh, uh, Wc, uc, inv_sigma);
  hipLaunchKernelGGL(prep_weights, dim3(576),  dim3(256), 0, stream,
                     Wf, Wg, Wh, Wc, inv_sigma, WallT, WcT);
  hipLaunchKernelGGL(fgh_kernel,   dim3(512),  dim3(256), 0, stream,
                     x, WallT, bf, bg, bh, fW, gW, hTW);
  hipLaunchKernelGGL(attn_kernel,  dim3(1024), dim3(256), 0, stream,
                     fW, gW, hTW, oPW, mPW, liPW);
  hipLaunchKernelGGL(out_kernel,   dim3(512),  dim3(256), 0, stream,
                     oPW, mPW, liPW, WcT, bc, x, gamma, out);
}

// Round 6
// 206.225 us; speedup vs baseline: 1.5022x; 1.0637x over previous
//
#include <hip/hip_runtime.h>

typedef unsigned short ushort_t;
typedef __attribute__((ext_vector_type(8))) __bf16 bf16x8;
typedef __attribute__((ext_vector_type(4))) float f32x4;
typedef __attribute__((ext_vector_type(4))) ushort_t ushort4_t;

__device__ inline ushort_t f2bf(float f){
  __bf16 h = (__bf16)f;
  union { __bf16 h; ushort_t u; } v; v.h = h;
  return v.u;
}

__device__ inline f32x4 mfma16(bf16x8 a, bf16x8 b, f32x4 c){
  return __builtin_amdgcn_mfma_f32_16x16x32_bf16(a, b, c, 0, 0, 0);
}

// direct global->LDS, 16B per lane; LDS dest wave-uniform base + lane*16
#define GLDS16(gsrc, ldst) \
  __builtin_amdgcn_global_load_lds((const __attribute__((address_space(1))) unsigned int*)(gsrc), \
                                   (__attribute__((address_space(3))) unsigned int*)(ldst), 16, 0, 0)

// ---------------- Kernel A1: spectral norm sigma (one block per weight) ----
__global__ void sigma_kernel(const float* __restrict__ Wf, const float* __restrict__ uf,
                             const float* __restrict__ Wg, const float* __restrict__ ug,
                             const float* __restrict__ Wh, const float* __restrict__ uh,
                             const float* __restrict__ Wc, const float* __restrict__ uc,
                             float* __restrict__ inv_sigma){
  int w = blockIdx.x, t = threadIdx.x;
  const float *W, *u; int Cout;
  if      (w == 0){ W = Wf; u = uf; Cout = 32; }
  else if (w == 1){ W = Wg; u = ug; Cout = 32; }
  else if (w == 2){ W = Wh; u = uh; Cout = 256; }
  else            { W = Wc; u = uc; Cout = 256; }
  __shared__ float su[256], sv[256], red[256];
  su[t] = u[t];
  __syncthreads();
  float v = 0.f;
  if (t < Cout){
    for (int i = 0; i < 256; ++i) v += W[i*Cout + t] * su[i];
  }
  red[t] = (t < Cout) ? v*v : 0.f;
  __syncthreads();
  for (int s = 128; s > 0; s >>= 1){ if (t < s) red[t] += red[t+s]; __syncthreads(); }
  float nv = sqrtf(red[0]) + 1e-12f;
  __syncthreads();
  if (t < Cout) sv[t] = v / nv;
  __syncthreads();
  float wv = 0.f;
  for (int d = 0; d < Cout; ++d) wv += W[t*Cout + d] * sv[d];
  __syncthreads();
  red[t] = wv * wv;
  __syncthreads();
  for (int s = 128; s > 0; s >>= 1){ if (t < s) red[t] += red[t+s]; __syncthreads(); }
  if (t == 0){
    float ss2 = red[0];
    float sig = ss2 / (sqrtf(ss2) + 1e-12f);   // sigma = u_new . (W v)
    inv_sigma[w] = 1.0f / sig;
  }
}

// ---------------- Kernel A2: transpose + 1/sigma fold + bf16 cast ----------
__global__ void prep_weights(const float* __restrict__ Wf, const float* __restrict__ Wg,
                             const float* __restrict__ Wh, const float* __restrict__ Wc,
                             const float* __restrict__ inv_sigma,
                             ushort_t* __restrict__ WallT, ushort_t* __restrict__ WcT){
  int idx = blockIdx.x * 256 + threadIdx.x;   // 0 .. 147455
  if (idx < 81920){                            // WallT[c][k], c in [0,320)
    int c = idx >> 8, k = idx & 255;
    float val, is;
    if (c < 32)      { val = Wf[k*32  + c      ]; is = inv_sigma[0]; }
    else if (c < 64) { val = Wg[k*32  + (c-32) ]; is = inv_sigma[1]; }
    else             { val = Wh[k*256 + (c-64) ]; is = inv_sigma[2]; }
    WallT[idx] = f2bf(val * is);
  } else {
    int j = idx - 81920; int c = j >> 8, k = j & 255;
    WcT[j] = f2bf(Wc[k*256 + c] * inv_sigma[3]);
  }
}

// ---------------- Kernel B: f,g,h = x @ [Wf|Wg|Wh]_sn + bias ---------------
// h is written KEY-PERMUTED within each 64-pixel tile so attention's PV can
// consume P directly from QK^T's register layout (see attn_kernel).
// s(k) = (k&32) | (((k>>2)&3)<<3) | (((k>>4)&1)<<2) | (k&3).
__global__ __launch_bounds__(256) void fgh_kernel(
    const float* __restrict__ x, const ushort_t* __restrict__ WallT,
    const float* __restrict__ bf, const float* __restrict__ bg, const float* __restrict__ bh,
    ushort_t* __restrict__ fO, ushort_t* __restrict__ gO, ushort_t* __restrict__ hT){
  __shared__ __attribute__((aligned(16))) char ldsX[4][16384];  // 16 rows x 1KB per wave
  int t = threadIdx.x;
  int wv = t >> 6, l = t & 63, lrow = l & 15, lgrp = l >> 4;
  long r0 = (long)blockIdx.x * 64 + wv * 16;
  char* ldsW = ldsX[wv];
#pragma unroll
  for (int rloc = 0; rloc < 16; ++rloc){
    const char* src = (const char*)(x + (r0 + rloc)*256)
                    + ((l*16) ^ ((rloc & 7) << 4));
    GLDS16(src, ldsW + rloc*1024);
  }
  asm volatile("s_waitcnt vmcnt(0)" ::: "memory");
  const char* xrow = ldsW + lrow*1024;
  int swzX = (lrow & 7) << 4;
  f32x4 acc[20];
#pragma unroll
  for (int i = 0; i < 20; ++i) acc[i] = f32x4{0.f,0.f,0.f,0.f};
#pragma unroll
  for (int ks = 0; ks < 8; ++ks){
    int bb = ks*128 + lgrp*32;
    f32x4 xa = *(const f32x4*)(xrow + ( bb       ^ swzX));
    f32x4 xb = *(const f32x4*)(xrow + ((bb + 16) ^ swzX));
    union { __bf16 h[8]; bf16x8 v; } A;
#pragma unroll
    for (int j = 0; j < 4; ++j){ A.h[j] = (__bf16)xa[j]; A.h[4+j] = (__bf16)xb[j]; }
    int kk = ks*32 + lgrp*8;
#pragma unroll
    for (int ct = 0; ct < 20; ++ct){
      bf16x8 bbv = *(const bf16x8*)(WallT + (ct*16 + lrow)*256 + kk);
      acc[ct] = mfma16(A.v, bbv, acc[ct]);
    }
  }
#pragma unroll
  for (int ct = 0; ct < 20; ++ct){
    int col = ct*16 + lrow;
    long rowb = r0 + lgrp*4;
    if (col < 32){
      float bv = bf[col];
#pragma unroll
      for (int rg = 0; rg < 4; ++rg) fO[(rowb+rg)*32 + col] = f2bf(acc[ct][rg] + bv);
    } else if (col < 64){
      float bv = bg[col-32];
#pragma unroll
      for (int rg = 0; rg < 4; ++rg)
        gO[(rowb+rg)*32 + (col-32)] = f2bf((acc[ct][rg] + bv) * 1.44269504f);
    } else {
      int hc = col - 64;
      float bv = bh[hc];
      long bb2 = rowb >> 12, n = rowb & 4095;
      int k6 = (int)(n & 63);
      int s6 = (k6 & 32) | (((k6 >> 2) & 3) << 3) | (((k6 >> 4) & 1) << 2) | (k6 & 3);
      long pos = (n & ~63L) | (long)s6;     // rowb%4==0 -> 4 consecutive slots
      ushort4_t pk;
#pragma unroll
      for (int rg = 0; rg < 4; ++rg) pk[rg] = f2bf(acc[ct][rg] + bv);
      *(ushort4_t*)(hT + (bb2*256 + hc)*4096 + pos) = pk;  // [b][d][key-slot]
    }
  }
}

// ---------------- Kernel C: flash attention v3, SPLIT-K ---------------------
// grid 512: b = bid&7 (XCD L2 pin), qt = (bid>>3)>>1 (128 q/block), kh = &1.
// 4 waves x 32 q-rows (2 q-tiles); each V b128 read feeds 2 MFMAs -> LDS
// read traffic halved vs 16q (the round-5 bottleneck: 4.3 GB LDS reads).
// P never touches LDS: PV computed as o^T = mfma(A=V, B=P) with V stored
// key-permuted (fgh) so QK^T's D-register layout IS the PV B-fragment.
// D col=q for both QK and PV -> per-lane softmax, shuffle-free rescale.
__global__ __launch_bounds__(256, 2) void attn_kernel(
    const ushort_t* __restrict__ fI, const ushort_t* __restrict__ gI,
    const ushort_t* __restrict__ hT,
    ushort_t* __restrict__ oP, float* __restrict__ mP, float* __restrict__ liP){
  __shared__ ushort_t ldsV[256*64];        // 32 KB: [d][key-slot], XOR-swizzled
  int bid = blockIdx.x, t = threadIdx.x;
  int b = bid & 7, rest = bid >> 3, qt = rest >> 1, kh = rest & 1;
  int wv = t >> 6, l = t & 63, lrow = l & 15, lgrp = l >> 4;
  int q0 = qt*128 + wv*32;
  long key_base = (long)kh * 2048;
  const ushort_t* gB = gI + ((long)b*4096 + q0)*32;
  bf16x8 qa0 = *(const bf16x8*)(gB + lrow*32 + lgrp*8);
  bf16x8 qa1 = *(const bf16x8*)(gB + (16 + lrow)*32 + lgrp*8);
  const ushort_t* hB = hT + (long)b*256*4096;
  const ushort_t* kp = fI + (long)b*4096*32 + key_base*32 + lrow*32 + lgrp*8;
  const ushort_t* vsrc = hB + (long)(wv*64 + (l>>3))*4096 + key_base
                            + (((l & 7) ^ (l >> 3)) << 3);
  ushort_t* vdst = ldsV + wv*4096;
  f32x4 o0[16], o1[16];
#pragma unroll
  for (int i = 0; i < 16; ++i){ o0[i] = f32x4{0.f,0.f,0.f,0.f}; o1[i] = f32x4{0.f,0.f,0.f,0.f}; }
  float m0 = -1e30f, m1 = -1e30f, li0 = 0.f, li1 = 0.f;   // per-lane, q = lrow (log2)
  int swzR = (lrow & 7) << 3;
  for (int kt = 0; kt < 32; ++kt){
    __syncthreads();                       // prev tile's ldsV reads complete
    bf16x8 kb0 = *(const bf16x8*)(kp);
    bf16x8 kb1 = *(const bf16x8*)(kp + 512);
    bf16x8 kb2 = *(const bf16x8*)(kp + 1024);
    bf16x8 kb3 = *(const bf16x8*)(kp + 1536);
    kp += 2048;
    const ushort_t* vs = vsrc + kt*64;
#pragma unroll
    for (int i = 0; i < 8; ++i)
      GLDS16(vs + i*32768, vdst + i*512);
    // swapped QK^T: s{qt}{st}[rg] = S[key = st*16+lgrp*4+rg][q = lrow]
    f32x4 s00 = mfma16(kb0, qa0, f32x4{0.f,0.f,0.f,0.f});
    f32x4 s01 = mfma16(kb1, qa0, f32x4{0.f,0.f,0.f,0.f});
    f32x4 s02 = mfma16(kb2, qa0, f32x4{0.f,0.f,0.f,0.f});
    f32x4 s03 = mfma16(kb3, qa0, f32x4{0.f,0.f,0.f,0.f});
    f32x4 s10 = mfma16(kb0, qa1, f32x4{0.f,0.f,0.f,0.f});
    f32x4 s11 = mfma16(kb1, qa1, f32x4{0.f,0.f,0.f,0.f});
    f32x4 s12 = mfma16(kb2, qa1, f32x4{0.f,0.f,0.f,0.f});
    f32x4 s13 = mfma16(kb3, qa1, f32x4{0.f,0.f,0.f,0.f});
    float tm0 = -1e30f, tm1 = -1e30f;
#pragma unroll
    for (int rg = 0; rg < 4; ++rg){
      tm0 = fmaxf(tm0, fmaxf(fmaxf(s00[rg], s01[rg]), fmaxf(s02[rg], s03[rg])));
      tm1 = fmaxf(tm1, fmaxf(fmaxf(s10[rg], s11[rg]), fmaxf(s12[rg], s13[rg])));
    }
    tm0 = fmaxf(tm0, __shfl_xor(tm0, 16)); tm0 = fmaxf(tm0, __shfl_xor(tm0, 32));
    tm1 = fmaxf(tm1, __shfl_xor(tm1, 16)); tm1 = fmaxf(tm1, __shfl_xor(tm1, 32));
    if (__any((tm0 > m0 + 8.f) || (tm1 > m1 + 8.f))){   // defer-max (T13)
      float mn0 = fmaxf(m0, tm0), mn1 = fmaxf(m1, tm1);
      float sc0 = exp2f(m0 - mn0), sc1 = exp2f(m1 - mn1);
      m0 = mn0; m1 = mn1; li0 *= sc0; li1 *= sc1;
#pragma unroll
      for (int ct = 0; ct < 16; ++ct)
#pragma unroll
        for (int rg = 0; rg < 4; ++rg){ o0[ct][rg] *= sc0; o1[ct][rg] *= sc1; }
    }
    // P = exp2(s-m) -> PV B-fragments entirely in registers.
    // frag n element j' = p[st = 2n + (j'>>2)][rg = j'&3]  (key-permuted V matches)
    union { __bf16 h[8]; bf16x8 v; } pf00, pf01, pf10, pf11;
#pragma unroll
    for (int rg = 0; rg < 4; ++rg){
      float a0 = exp2f(s00[rg] - m0), a1 = exp2f(s01[rg] - m0);
      float a2 = exp2f(s02[rg] - m0), a3 = exp2f(s03[rg] - m0);
      li0 += (a0 + a1) + (a2 + a3);
      pf00.h[rg] = (__bf16)a0; pf00.h[4+rg] = (__bf16)a1;
      pf01.h[rg] = (__bf16)a2; pf01.h[4+rg] = (__bf16)a3;
      float c0 = exp2f(s10[rg] - m1), c1 = exp2f(s11[rg] - m1);
      float c2 = exp2f(s12[rg] - m1), c3 = exp2f(s13[rg] - m1);
      li1 += (c0 + c1) + (c2 + c3);
      pf10.h[rg] = (__bf16)c0; pf10.h[4+rg] = (__bf16)c1;
      pf11.h[rg] = (__bf16)c2; pf11.h[4+rg] = (__bf16)c3;
    }
    asm volatile("s_waitcnt vmcnt(0)" ::: "memory");   // V tile landed in LDS
    __syncthreads();                       // all waves' V visible
    __builtin_amdgcn_s_setprio(1);
#pragma unroll
    for (int ct = 0; ct < 16; ++ct){
      int base = (ct*16 + lrow) << 6;
      bf16x8 vb0 = *(const bf16x8*)(ldsV + base + (( (lgrp << 3))      ^ swzR));
      bf16x8 vb1 = *(const bf16x8*)(ldsV + base + ((32 + (lgrp << 3)) ^ swzR));
      o0[ct] = mfma16(vb0, pf00.v, o0[ct]);   // vb reused across both q-tiles
      o0[ct] = mfma16(vb1, pf01.v, o0[ct]);
      o1[ct] = mfma16(vb0, pf10.v, o1[ct]);
      o1[ct] = mfma16(vb1, pf11.v, o1[ct]);
    }
    __builtin_amdgcn_s_setprio(0);
  }
  li0 += __shfl_xor(li0, 16); li0 += __shfl_xor(li0, 32);
  li1 += __shfl_xor(li1, 16); li1 += __shfl_xor(li1, 32);
  long rbase = (long)b*4096 + q0;
  ushort_t* Ob = oP + ((long)kh*32768 + rbase)*256;
  // D layout: col = q = lrow(+16 for qt1), row = d = ct*16 + lgrp*4 + rg
#pragma unroll
  for (int ct = 0; ct < 16; ++ct){
    ushort4_t pk0, pk1;
#pragma unroll
    for (int rg = 0; rg < 4; ++rg){ pk0[rg] = f2bf(o0[ct][rg]); pk1[rg] = f2bf(o1[ct][rg]); }
    *(ushort4_t*)(Ob + (long)lrow*256      + ct*16 + lgrp*4) = pk0;
    *(ushort4_t*)(Ob + (long)(16+lrow)*256 + ct*16 + lgrp*4) = pk1;
  }
  if (l < 16){
    mP [kh*32768 + rbase + lrow]      = m0;
    liP[kh*32768 + rbase + lrow]      = li0;
    mP [kh*32768 + rbase + 16 + lrow] = m1;
    liP[kh*32768 + rbase + 16 + lrow] = li1;
  }
}

// ---------------- Kernel D: combine split-K + out = gamma*(O@Wc + bc) + x --
__global__ __launch_bounds__(256) void out_kernel(
    const ushort_t* __restrict__ oP, const float* __restrict__ mP,
    const float* __restrict__ liP, const ushort_t* __restrict__ WcT,
    const float* __restrict__ bc, const float* __restrict__ x,
    const float* __restrict__ gamma, float* __restrict__ out){
  __shared__ __attribute__((aligned(16))) char ldsO[4][16384]; // per wave: o1 8KB | o2 8KB
  int t = threadIdx.x;
  int wv = t >> 6, l = t & 63, lrow = l & 15, lgrp = l >> 4;
  long r0 = (long)blockIdx.x * 64 + wv * 16;
  char* ldsW = ldsO[wv];
#pragma unroll
  for (int i = 0; i < 8; ++i){
    int rloc = 2*i + (l >> 5);
    int soff = ((l & 31)*16) ^ ((rloc & 7) << 4);
    GLDS16((const char*)(oP + (r0 + rloc)*256) + soff,            ldsW + i*1024);
    GLDS16((const char*)(oP + (32768L + r0 + rloc)*256) + soff,   ldsW + 8192 + i*1024);
  }
  long r = r0 + lrow;
  float m1 = mP[r],  m2 = mP[32768 + r];
  float li1 = liP[r], li2 = liP[32768 + r];
  float mm  = fmaxf(m1, m2);
  float sc1 = exp2f(m1 - mm), sc2 = exp2f(m2 - mm);
  float inv = 1.0f / (li1*sc1 + li2*sc2);
  float w1 = sc1 * inv, w2 = sc2 * inv;
  asm volatile("s_waitcnt vmcnt(0)" ::: "memory");
  const char* orow = ldsW + lrow*512;
  int swzO = (lrow & 7) << 4;
  f32x4 acc[16];
#pragma unroll
  for (int i = 0; i < 16; ++i) acc[i] = f32x4{0.f,0.f,0.f,0.f};
#pragma unroll
  for (int ks = 0; ks < 8; ++ks){
    int bb = (ks*64 + lgrp*16) ^ swzO;
    bf16x8 a1 = *(const bf16x8*)(orow + bb);
    bf16x8 a2 = *(const bf16x8*)(orow + 8192 + bb);
    union { __bf16 h[8]; bf16x8 v; } A;
#pragma unroll
    for (int j = 0; j < 8; ++j)
      A.h[j] = (__bf16)((float)a1[j]*w1 + (float)a2[j]*w2);
    int kk = ks*32 + lgrp*8;
#pragma unroll
    for (int ct = 0; ct < 16; ++ct){
      bf16x8 bbv = *(const bf16x8*)(WcT + (ct*16 + lrow)*256 + kk);
      acc[ct] = mfma16(A.v, bbv, acc[ct]);
    }
  }
  float gm = gamma[0];
#pragma unroll
  for (int ct = 0; ct < 16; ++ct){
    int col = ct*16 + lrow;
    float bv = bc[col];
#pragma unroll
    for (int rg = 0; rg < 4; ++rg){
      long row = r0 + lgrp*4 + rg;
      out[row*256 + col] = gm*(acc[ct][rg] + bv) + x[row*256 + col];
    }
  }
}

extern "C" void kernel_launch(void* const* d_in, const int* in_sizes, int n_in,
                              void* d_out, int out_size, void* d_ws, size_t ws_size,
                              hipStream_t stream){
  (void)in_sizes; (void)n_in; (void)out_size; (void)ws_size;
  const float* x  = (const float*)d_in[0];
  const float* Wf = (const float*)d_in[1];
  const float* bf = (const float*)d_in[2];
  const float* uf = (const float*)d_in[3];
  const float* Wg = (const float*)d_in[4];
  const float* bg = (const float*)d_in[5];
  const float* ug = (const float*)d_in[6];
  const float* Wh = (const float*)d_in[7];
  const float* bh = (const float*)d_in[8];
  const float* uh = (const float*)d_in[9];
  const float* Wc = (const float*)d_in[10];
  const float* bc = (const float*)d_in[11];
  const float* uc = (const float*)d_in[12];
  const float* gamma = (const float*)d_in[13];
  float* out = (float*)d_out;

  char* w = (char*)d_ws;
  float*    inv_sigma = (float*)w;                         // @0,     256 B
  ushort_t* WallT = (ushort_t*)(w + 256);                  // 163840
  ushort_t* WcT   = (ushort_t*)(w + 164096);               // 131072
  ushort_t* fW    = (ushort_t*)(w + 295168);               // 2 MB
  ushort_t* gW    = (ushort_t*)(w + 2392320);              // 2 MB
  ushort_t* hTW   = (ushort_t*)(w + 4489472);              // 16 MB (key-permuted)
  ushort_t* oPW   = (ushort_t*)(w + 21266688);             // 32 MB (2 x 8x4096x256 bf16)
  float*    mPW   = (float*)   (w + 54821120);             // 256 KB
  float*    liPW  = (float*)   (w + 55083264);             // 256 KB  -> total ~55.3 MB

  hipLaunchKernelGGL(sigma_kernel, dim3(4),    dim3(256), 0, stream,
                     Wf, uf, Wg, ug, Wh, uh, Wc, uc, inv_sigma);
  hipLaunchKernelGGL(prep_weights, dim3(576),  dim3(256), 0, stream,
                     Wf, Wg, Wh, Wc, inv_sigma, WallT, WcT);
  hipLaunchKernelGGL(fgh_kernel,   dim3(512),  dim3(256), 0, stream,
                     x, WallT, bf, bg, bh, fW, gW, hTW);
  hipLaunchKernelGGL(attn_kernel,  dim3(512),  dim3(256), 0, stream,
                     fW, gW, hTW, oPW, mPW, liPW);
  hipLaunchKernelGGL(out_kernel,   dim3(512),  dim3(256), 0, stream,
                     oPW, mPW, liPW, WcT, bc, x, gamma, out);
}